// Round 1
// baseline (371.192 us; speedup 1.0000x reference)
//
#include <hip/hip_runtime.h>

// ---------------------------------------------------------------------------
// MaskedAutoregressiveFlow (RealNVP coupling) fused kernel for gfx950.
// B=16384 rows, F=64, CTX=128, HID=512, L=8 layers, NB=2 hidden blocks.
//
// Plan:
//  1) pack_weights_kernel: fp32 -> bf16, pre-swizzled into MFMA B-fragment
//     order: [k_chunk][n_tile][lane][8 contiguous k]  (one coalesced
//     global_load_dwordx4 per fragment in the GEMM loop).
//  2) flow_kernel<true>: 256 blocks x 256 threads; block owns 64 rows and
//     runs all 8 layers fully fused. h ping-pongs between two LDS buffers
//     (64 x 520 bf16). mfma_f32_16x16x32_bf16; 4 waves split N into 128-wide
//     strips; weights reused across all 4 m-tiles from registers (each
//     weight byte crosses L2 exactly once per block).
//  If ws_size is too small for the packed weights, flow_kernel<false>
//  gathers raw fp32 weights directly (slow but correct).
// ---------------------------------------------------------------------------

typedef short v8s __attribute__((ext_vector_type(8)));   // 8 x bf16
typedef float v4f __attribute__((ext_vector_type(4)));   // MFMA acc

#define BATCH 16384
#define NF    64
#define NCTX  128
#define NHID  512
#define NL    8

#define AST   520   // LDS h/A row stride in bf16 elems (520*2B = 65 x 16B -> odd superbank stride)
#define PST   68    // LDS p row stride in floats (breaks 32-bank aliasing)

// packed-weight element offsets (bf16 elements)
#define WIN_EPL   (160 * 512)                               // 81920 / layer
#define WH_EPB    (512 * 512)                               // 262144 / (layer,block)
#define WOUT_EPL  (512 * 64)                                // 32768 / layer
#define OFF_WIN   ((size_t)0)
#define OFF_WH    ((size_t)(8 * WIN_EPL))                   // 655360
#define OFF_WOUT  (OFF_WH + (size_t)(16 * WH_EPB))          // 4849664
#define TOT_PACK_ELEMS (OFF_WOUT + (size_t)(8 * WOUT_EPL))  // 5111808
#define NEED_WS   (TOT_PACK_ELEMS * 2)                      // 10,223,616 B

// fp32 -> bf16, round-to-nearest-even
__device__ __forceinline__ unsigned short f2b(float f) {
    union { float f; unsigned int u; } x; x.f = f;
    unsigned int r = x.u + 0x7FFFu + ((x.u >> 16) & 1u);
    return (unsigned short)(r >> 16);
}

// packed index of element W[k][n] for a stage with NT n-tiles of 16:
// lane = ((k&31)>>3)*16 + (n&15), j = k&7  ->  frag base (kc,nt)*64 lanes*8
__device__ __forceinline__ size_t pidx(int k, int n, int NT) {
    return ((size_t)((k >> 5) * NT + (n >> 4))) * 512
         + (size_t)((((k >> 3) & 3) << 7) + ((n & 15) << 3) + (k & 7));
}

__global__ void pack_weights_kernel(const float* __restrict__ W_in,
                                    const float* __restrict__ W_h,
                                    const float* __restrict__ W_out,
                                    unsigned short* __restrict__ ws) {
    const int WIN_E  = 8 * WIN_EPL;     // 655360
    const int WH_E   = 16 * WH_EPB;     // 4194304
    const int WOUT_E = 8 * WOUT_EPL;    // 262144
    const int total  = WIN_E + WH_E + WOUT_E;
    for (int t = blockIdx.x * blockDim.x + threadIdx.x; t < total;
         t += gridDim.x * blockDim.x) {
        float val; size_t dest;
        if (t < WIN_E) {
            int i = t / WIN_EPL, r = t - i * WIN_EPL;
            int k = r >> 9, n = r & 511;
            val  = W_in[t];
            dest = OFF_WIN + (size_t)i * WIN_EPL + pidx(k, n, 32);
        } else if (t < WIN_E + WH_E) {
            int u = t - WIN_E;
            int ij = u / WH_EPB, r = u - ij * WH_EPB;
            int k = r >> 9, n = r & 511;
            val  = W_h[u];
            dest = OFF_WH + (size_t)ij * WH_EPB + pidx(k, n, 32);
        } else {
            int u = t - WIN_E - WH_E;
            int i = u / WOUT_EPL, r = u - i * WOUT_EPL;
            int k = r >> 6, n = r & 63;
            val  = W_out[u];
            dest = OFF_WOUT + (size_t)i * WOUT_EPL + pidx(k, n, 4);
        }
        ws[dest] = f2b(val);
    }
}

__device__ __forceinline__ v4f mfma_bf16(v8s a, v8s b, v4f c) {
    return __builtin_amdgcn_mfma_f32_16x16x32_bf16(a, b, c, 0, 0, 0);
}

// One GEMM stage: out[M=64, N=NTW*4*16] = act(A[64,KC*32] @ W + bias)
// A in LDS (stride AST bf16). RELU path writes bf16 to Obuf (stride AST);
// else writes fp32 to Pbuf (stride PST). Wave w owns n-tiles [w*NTW, (w+1)*NTW).
template<int KC, int NTW, bool PACKED, bool RELU>
__device__ __forceinline__ void gemm_stage(
    const unsigned short* __restrict__ wpk,
    const float* __restrict__ wraw, int rawN,
    const float* __restrict__ bias,
    const unsigned short* __restrict__ Abuf,
    unsigned short* __restrict__ Obuf,
    float* __restrict__ Pbuf,
    int wave, int lane)
{
    const int quad = lane >> 4, l15 = lane & 15;
    const int NTtot = NTW * 4;
    const int ntb = wave * NTW;
    v4f acc[4][NTW];
#pragma unroll
    for (int mt = 0; mt < 4; ++mt)
#pragma unroll
        for (int t = 0; t < NTW; ++t) {
            acc[mt][t][0] = 0.f; acc[mt][t][1] = 0.f;
            acc[mt][t][2] = 0.f; acc[mt][t][3] = 0.f;
        }
#pragma unroll
    for (int kc = 0; kc < KC; ++kc) {
        v8s a[4];
#pragma unroll
        for (int mt = 0; mt < 4; ++mt)
            a[mt] = *(const v8s*)(Abuf + (mt * 16 + l15) * AST + kc * 32 + quad * 8);
        v8s b[NTW];
#pragma unroll
        for (int t = 0; t < NTW; ++t) {
            if constexpr (PACKED) {
                b[t] = *(const v8s*)(wpk + ((size_t)((kc * NTtot + ntb + t) * 64 + lane)) * 8);
            } else {
                int k0 = kc * 32 + quad * 8;
                int n  = (ntb + t) * 16 + l15;
                v8s bb;
#pragma unroll
                for (int j = 0; j < 8; ++j)
                    bb[j] = (short)f2b(wraw[(size_t)(k0 + j) * rawN + n]);
                b[t] = bb;
            }
        }
#pragma unroll
        for (int mt = 0; mt < 4; ++mt)
#pragma unroll
            for (int t = 0; t < NTW; ++t)
                acc[mt][t] = mfma_bf16(a[mt], b[t], acc[mt][t]);
    }
    // epilogue: D layout col = lane&15, row = quad*4 + reg (per m-tile)
#pragma unroll
    for (int t = 0; t < NTW; ++t) {
        int n = (ntb + t) * 16 + l15;
        float bv = bias[n];
#pragma unroll
        for (int mt = 0; mt < 4; ++mt) {
#pragma unroll
            for (int r = 0; r < 4; ++r) {
                int row = mt * 16 + quad * 4 + r;
                float v = acc[mt][t][r] + bv;
                if constexpr (RELU) {
                    v = v > 0.f ? v : 0.f;
                    Obuf[row * AST + n] = f2b(v);
                } else {
                    Pbuf[row * PST + n] = v;
                }
            }
        }
    }
}

template<bool PACKED>
__global__ __launch_bounds__(256, 1) void flow_kernel(
    const float* __restrict__ inputs,
    const float* __restrict__ ctx,
    const float* __restrict__ W_in,  const float* __restrict__ b_in,
    const float* __restrict__ W_h,   const float* __restrict__ b_h,
    const float* __restrict__ W_out, const float* __restrict__ b_out,
    const int*   __restrict__ perms,
    const unsigned short* __restrict__ wpk,
    float* __restrict__ out)
{
    __shared__ __align__(16) unsigned short hbuf0[64 * AST];  // 66,560 B
    __shared__ __align__(16) unsigned short hbuf1[64 * AST];  // 66,560 B
    __shared__ __align__(16) float xbuf[64 * NF];             // 16,384 B
    __shared__ int permsh[NF];

    float* pbuf    = (float*)hbuf0;   // p (64 x 64 fp32, stride PST) after G3
    float* scratch = (float*)hbuf1;   // permutation scratch (64 x 64 fp32)

    const int tid  = threadIdx.x;
    const int wave = tid >> 6;
    const int lane = tid & 63;
    const int trow = tid >> 2;        // 0..63 : row owned in elementwise phases
    const int tq   = tid & 3;         // 0..3  : quarter of that row
    const int row0 = blockIdx.x * 64;

    // ---- load + clip x tile
    {
        const float4* in4 = (const float4*)(inputs + (size_t)row0 * NF);
        float4* x4 = (float4*)xbuf;
#pragma unroll
        for (int u = 0; u < 4; ++u) {
            float4 v = in4[trow * 16 + tq * 4 + u];
            v.x = fminf(fmaxf(v.x, -1.f), 1.f);
            v.y = fminf(fmaxf(v.y, -1.f), 1.f);
            v.z = fminf(fmaxf(v.z, -1.f), 1.f);
            v.w = fminf(fmaxf(v.w, -1.f), 1.f);
            x4[trow * 16 + tq * 4 + u] = v;
        }
    }
    float ld_acc = 0.f;
    __syncthreads();

#pragma unroll 1
    for (int i = 0; i < NL; ++i) {
        const int par = i & 1;        // t_idx parity (even layer -> even cols)
        const int idp = par ^ 1;      // id_idx parity

        // ---- stage A0 = [id_split(32) | context(128)] bf16 into hbuf0
        {
            v8s pk;
#pragma unroll
            for (int j = 0; j < 8; ++j) {
                int c = tq * 8 + j;
                pk[j] = (short)f2b(xbuf[trow * NF + 2 * c + idp]);
            }
            *(v8s*)(hbuf0 + trow * AST + tq * 8) = pk;

            const float* crow = ctx + (size_t)(row0 + trow) * NCTX + tq * 32;
#pragma unroll
            for (int g = 0; g < 4; ++g) {
                float4 f0 = ((const float4*)crow)[g * 2];
                float4 f1 = ((const float4*)crow)[g * 2 + 1];
                v8s ck;
                ck[0] = (short)f2b(f0.x); ck[1] = (short)f2b(f0.y);
                ck[2] = (short)f2b(f0.z); ck[3] = (short)f2b(f0.w);
                ck[4] = (short)f2b(f1.x); ck[5] = (short)f2b(f1.y);
                ck[6] = (short)f2b(f1.z); ck[7] = (short)f2b(f1.w);
                *(v8s*)(hbuf0 + trow * AST + 32 + tq * 32 + g * 8) = ck;
            }
        }
        __syncthreads();

        // ---- G0: h = relu([id|ctx] @ W_in + b_in)   (K=160)
        gemm_stage<5, 8, PACKED, true>(
            PACKED ? wpk + OFF_WIN + (size_t)i * WIN_EPL : (const unsigned short*)nullptr,
            W_in + (size_t)i * WIN_EPL, 512, b_in + i * 512,
            hbuf0, hbuf1, nullptr, wave, lane);
        __syncthreads();
        // ---- G1
        gemm_stage<16, 8, PACKED, true>(
            PACKED ? wpk + OFF_WH + (size_t)(i * 2 + 0) * WH_EPB : (const unsigned short*)nullptr,
            W_h + (size_t)(i * 2 + 0) * WH_EPB, 512, b_h + (i * 2 + 0) * 512,
            hbuf1, hbuf0, nullptr, wave, lane);
        __syncthreads();
        // ---- G2
        gemm_stage<16, 8, PACKED, true>(
            PACKED ? wpk + OFF_WH + (size_t)(i * 2 + 1) * WH_EPB : (const unsigned short*)nullptr,
            W_h + (size_t)(i * 2 + 1) * WH_EPB, 512, b_h + (i * 2 + 1) * 512,
            hbuf0, hbuf1, nullptr, wave, lane);
        __syncthreads();
        // ---- G3: p = h @ W_out + b_out  (N=64, fp32 out into pbuf)
        gemm_stage<16, 1, PACKED, false>(
            PACKED ? wpk + OFF_WOUT + (size_t)i * WOUT_EPL : (const unsigned short*)nullptr,
            W_out + (size_t)i * WOUT_EPL, 64, b_out + i * 64,
            hbuf1, nullptr, pbuf, wave, lane);
        __syncthreads();

        // ---- coupling: shift = p[:, :32]; scale = sigmoid(p[:,32:]+2)+1e-3
        {
#pragma unroll
            for (int j = 0; j < 8; ++j) {
                int sc = tq * 8 + j;
                float shiftv = pbuf[trow * PST + sc];
                float z = pbuf[trow * PST + 32 + sc] + 2.0f;
                float s = 1.0f / (1.0f + __expf(-z)) + 0.001f;
                int tc = 2 * sc + par;
                xbuf[trow * NF + tc] = xbuf[trow * NF + tc] * s + shiftv;
                ld_acc += __logf(s);
            }
        }
        __syncthreads();

        // ---- permutation: x = x[:, perm[i]]
        if (i < NL - 1) {
            float4* x4 = (float4*)xbuf;
            float4* s4 = (float4*)scratch;
#pragma unroll
            for (int u = 0; u < 4; ++u) s4[tid * 4 + u] = x4[tid * 4 + u];
            if (tid < NF) permsh[tid] = perms[i * NF + tid];
            __syncthreads();
#pragma unroll
            for (int j = 0; j < 16; ++j) {
                int c = tq * 16 + j;
                xbuf[trow * NF + c] = scratch[trow * NF + permsh[c]];
            }
            __syncthreads();
        }
    }

    // ---- outputs: clip(x) then logdet
    {
        float4* x4 = (float4*)xbuf;
        float4* o4 = (float4*)(out + (size_t)row0 * NF);
#pragma unroll
        for (int u = 0; u < 4; ++u) {
            float4 v = x4[trow * 16 + tq * 4 + u];
            v.x = fminf(fmaxf(v.x, -1.f), 1.f);
            v.y = fminf(fmaxf(v.y, -1.f), 1.f);
            v.z = fminf(fmaxf(v.z, -1.f), 1.f);
            v.w = fminf(fmaxf(v.w, -1.f), 1.f);
            o4[trow * 16 + tq * 4 + u] = v;
        }
    }
    // reduce 4 partials per row (lanes 4r..4r+3 are consecutive in a wave)
    ld_acc += __shfl_down(ld_acc, 1);
    ld_acc += __shfl_down(ld_acc, 2);
    if (tq == 0) out[(size_t)BATCH * NF + row0 + trow] = ld_acc;
}

extern "C" void kernel_launch(void* const* d_in, const int* in_sizes, int n_in,
                              void* d_out, int out_size, void* d_ws, size_t ws_size,
                              hipStream_t stream) {
    const float* inputs  = (const float*)d_in[0];
    const float* context = (const float*)d_in[1];
    const float* W_in    = (const float*)d_in[2];
    const float* b_in    = (const float*)d_in[3];
    const float* W_h     = (const float*)d_in[4];
    const float* b_h     = (const float*)d_in[5];
    const float* W_out   = (const float*)d_in[6];
    const float* b_out   = (const float*)d_in[7];
    const int*   perms   = (const int*)d_in[8];
    float* out = (float*)d_out;

    if (ws_size >= (size_t)NEED_WS) {
        unsigned short* ws = (unsigned short*)d_ws;
        pack_weights_kernel<<<512, 256, 0, stream>>>(W_in, W_h, W_out, ws);
        flow_kernel<true><<<256, 256, 0, stream>>>(
            inputs, context, W_in, b_in, W_h, b_h, W_out, b_out, perms, ws, out);
    } else {
        flow_kernel<false><<<256, 256, 0, stream>>>(
            inputs, context, W_in, b_in, W_h, b_h, W_out, b_out, perms,
            (const unsigned short*)nullptr, out);
    }
}